// Round 2
// baseline (261.427 us; speedup 1.0000x reference)
//
#include <hip/hip_runtime.h>
#include <stdint.h>

#define HW 4096
#define NC 512
#define NB 8

typedef __attribute__((ext_vector_type(8))) short short8;
typedef __attribute__((ext_vector_type(4))) float f32x4;

__device__ __forceinline__ unsigned short f2bf(float f) {
  unsigned int u = __builtin_bit_cast(unsigned int, f);
  unsigned int r = (u + 0x7FFFu + ((u >> 16) & 1u)) >> 16;
  return (unsigned short)r;
}
__device__ __forceinline__ float hsig(float v) {
  return fminf(fmaxf((v + 3.0f) * (1.0f / 6.0f), 0.0f), 1.0f);
}

__device__ __forceinline__ float block_reduce_sum(float v, volatile float* red) {
  int t = threadIdx.x;
#pragma unroll
  for (int m = 1; m < 64; m <<= 1) v += __shfl_xor(v, m);
  if ((t & 63) == 0) red[t >> 6] = v;
  __syncthreads();
  v = red[0] + red[1] + red[2] + red[3];
  __syncthreads();
  return v;
}
__device__ __forceinline__ float block_reduce_max(float v, volatile float* red) {
  int t = threadIdx.x;
#pragma unroll
  for (int m = 1; m < 64; m <<= 1) v = fmaxf(v, __shfl_xor(v, m));
  if ((t & 63) == 0) red[t >> 6] = v;
  __syncthreads();
  v = fmaxf(fmaxf(red[0], red[1]), fmaxf(red[2], red[3]));
  __syncthreads();
  return v;
}

// K1: one pass over x. Per 64c x 64hw tile: partial g (mean over hw), partial
// spatial dot (over c), and bf16 transpose-out xT[b][hw][c].
__global__ __launch_bounds__(256) void k1_stats_transpose(
    const float* __restrict__ x, const float* __restrict__ w_conv1,
    float* __restrict__ g_sum, float* __restrict__ spat,
    unsigned short* __restrict__ xT) {
  __shared__ float sp_lds[16][64];
  __shared__ unsigned short t_lds[64 * 72];  // [hw][c], pad 72 (rows 144B, 16B-aligned)
  const int t = threadIdx.x;
  const int b = blockIdx.z;
  const int c0 = blockIdx.y * 64;
  const int h0 = blockIdx.x * 64;
  const int cg = t >> 4;   // 0..15 -> 4 c rows each
  const int hg = t & 15;   // 0..15 -> 4 hw each

  float vv[4][4];
  float wc[4];
  const float* xb = x + ((size_t)(b * NC + c0 + cg * 4) * HW) + h0 + hg * 4;
#pragma unroll
  for (int i = 0; i < 4; i++) {
    float4 v = *(const float4*)(xb + (size_t)i * HW);
    vv[i][0] = v.x; vv[i][1] = v.y; vv[i][2] = v.z; vv[i][3] = v.w;
    wc[i] = w_conv1[c0 + cg * 4 + i];
  }
  // g partial: reduce each c-row's 4hw sum across the 16 hg lanes (same wave)
#pragma unroll
  for (int i = 0; i < 4; i++) {
    float s = vv[i][0] + vv[i][1] + vv[i][2] + vv[i][3];
    s += __shfl_xor(s, 1); s += __shfl_xor(s, 2);
    s += __shfl_xor(s, 4); s += __shfl_xor(s, 8);
    if (hg == 0) atomicAdd(&g_sum[b * NC + c0 + cg * 4 + i], s);
  }
  // spatial partial: this thread's 4-c contribution for its 4 hw
  {
    float4 sp;
    sp.x = vv[0][0] * wc[0] + vv[1][0] * wc[1] + vv[2][0] * wc[2] + vv[3][0] * wc[3];
    sp.y = vv[0][1] * wc[0] + vv[1][1] * wc[1] + vv[2][1] * wc[2] + vv[3][1] * wc[3];
    sp.z = vv[0][2] * wc[0] + vv[1][2] * wc[1] + vv[2][2] * wc[2] + vv[3][2] * wc[3];
    sp.w = vv[0][3] * wc[0] + vv[1][3] * wc[1] + vv[2][3] * wc[2] + vv[3][3] * wc[3];
    *(float4*)&sp_lds[cg][hg * 4] = sp;
  }
  // bf16 transpose into LDS: rows = hw, cols = c
#pragma unroll
  for (int j = 0; j < 4; j++) {
    ushort4 u;
    u.x = f2bf(vv[0][j]); u.y = f2bf(vv[1][j]);
    u.z = f2bf(vv[2][j]); u.w = f2bf(vv[3][j]);
    *(ushort4*)&t_lds[(hg * 4 + j) * 72 + cg * 4] = u;
  }
  __syncthreads();
  if (t < 64) {
    float s = 0.f;
#pragma unroll
    for (int i = 0; i < 16; i++) s += sp_lds[i][t];
    atomicAdd(&spat[b * HW + h0 + t], s);
  }
  // coalesced write-out: 64 rows x 128B
#pragma unroll
  for (int q = t; q < 512; q += 256) {
    int r = q >> 3, p = q & 7;
    short8 v = *(const short8*)&t_lds[r * 72 + p * 8];
    *(short8*)(xT + (size_t)(b * HW + h0 + r) * NC + c0 + p * 8) = v;
  }
}

// K2_prep: blocks 0..31: s = hsigmoid(spat), Ssum[b]; blocks 32..159: res_w -> bf16
__global__ __launch_bounds__(256) void k2_prep(
    const float* __restrict__ spat, float* __restrict__ s, float* __restrict__ Ssum,
    const float* __restrict__ res_w, unsigned short* __restrict__ wbf) {
  __shared__ float red[4];
  const int blk = blockIdx.x, t = threadIdx.x;
  if (blk < 32) {
    int idx = blk * 1024 + t * 4;
    int b = idx >> 12;
    float4 v = *(const float4*)(spat + idx);
    float4 o;
    o.x = hsig(v.x); o.y = hsig(v.y); o.z = hsig(v.z); o.w = hsig(v.w);
    *(float4*)(s + idx) = o;
    float sum = block_reduce_sum(o.x + o.y + o.z + o.w, red);
    if (t == 0) atomicAdd(&Ssum[b], sum);
  } else {
    int i = (blk - 32) * 2048 + t * 8;
    float4 a = *(const float4*)(res_w + i);
    float4 c = *(const float4*)(res_w + i + 4);
    short8 v;
    v[0] = (short)f2bf(a.x); v[1] = (short)f2bf(a.y);
    v[2] = (short)f2bf(a.z); v[3] = (short)f2bf(a.w);
    v[4] = (short)f2bf(c.x); v[5] = (short)f2bf(c.y);
    v[6] = (short)f2bf(c.z); v[7] = (short)f2bf(c.w);
    *(short8*)(wbf + i) = v;
  }
}

// K2a: g -> bottleneck MLP -> hsigmoid -> LayerNorm -> t[b][c]
__global__ __launch_bounds__(256) void k2a_chain(
    const float* __restrict__ g_sum, const float* __restrict__ w_b1,
    const float* __restrict__ b_b1, const float* __restrict__ w_b2,
    const float* __restrict__ b_b2, const float* __restrict__ ln_g,
    const float* __restrict__ ln_b, float* __restrict__ t_out) {
  __shared__ float g_l[512];
  __shared__ float ca1_l[256];
  __shared__ float red[4];
  const int b = blockIdx.x, t = threadIdx.x;
  g_l[t] = g_sum[b * NC + t] * (1.0f / 4096.0f);
  g_l[t + 256] = g_sum[b * NC + t + 256] * (1.0f / 4096.0f);
  __syncthreads();
  {
    float acc = b_b1[t];
    const float4* wr = (const float4*)(w_b1 + (size_t)t * 512);
    for (int i = 0; i < 128; i++) {
      float4 w = wr[i];
      acc += w.x * g_l[i * 4] + w.y * g_l[i * 4 + 1] + w.z * g_l[i * 4 + 2] + w.w * g_l[i * 4 + 3];
    }
    ca1_l[t] = fmaxf(acc, 0.0f);
  }
  __syncthreads();
  float ca[2];
#pragma unroll
  for (int h = 0; h < 2; h++) {
    int o = t + h * 256;
    float acc = b_b2[o];
    const float4* wr = (const float4*)(w_b2 + (size_t)o * 256);
    for (int i = 0; i < 64; i++) {
      float4 w = wr[i];
      acc += w.x * ca1_l[i * 4] + w.y * ca1_l[i * 4 + 1] + w.z * ca1_l[i * 4 + 2] + w.w * ca1_l[i * 4 + 3];
    }
    ca[h] = hsig(acc);
  }
  float S = block_reduce_sum(ca[0] + ca[1], red);
  float SQ = block_reduce_sum(ca[0] * ca[0] + ca[1] * ca[1], red);
  float mu = S * (1.0f / 512.0f);
  float var = SQ * (1.0f / 512.0f) - mu * mu;
  float rstd = rsqrtf(var + 1e-6f);
#pragma unroll
  for (int h = 0; h < 2; h++) {
    int o = t + h * 256;
    t_out[b * NC + o] = (ca[h] - mu) * rstd * ln_g[o] + ln_b[o];
  }
}

// K2b: P[b][c] = sum_hw floor((s + t)/2). s[b][:] staged once in LDS,
// one wave per channel (no block barrier in the reduce).
__global__ __launch_bounds__(256) void k2b_floorsum(
    const float* __restrict__ s, const float* __restrict__ t_arr, float* __restrict__ P) {
  __shared__ float s_l[4096];
  const int t = threadIdx.x;
  const int b = blockIdx.y;
  const int c0 = blockIdx.x * 16;
  const float* sb = s + b * HW;
#pragma unroll
  for (int i = 0; i < 16; i++) s_l[t + i * 256] = sb[t + i * 256];
  __syncthreads();
  const int w = t >> 6, l = t & 63;
#pragma unroll
  for (int j = 0; j < 4; j++) {
    int c = c0 + w * 4 + j;
    float tc = t_arr[b * NC + c];
    float sum = 0.f;
#pragma unroll 8
    for (int i = 0; i < 64; i++) sum += floorf((s_l[l + i * 64] + tc) * 0.5f);
#pragma unroll
    for (int m = 1; m < 64; m <<= 1) sum += __shfl_xor(sum, m);
    if (l == 0) P[b * NC + c] = sum;
  }
}

// K2c: u -> SK MLP -> softmax -> coef[b][c] = {a*t, 1-a, selected_sum, t}
__global__ __launch_bounds__(256) void k2c_select(
    const float* __restrict__ t_arr, const float* __restrict__ P,
    const float* __restrict__ Ssum, const float* __restrict__ sk_w1,
    const float* __restrict__ sk_w2, float* __restrict__ coef) {
  __shared__ float u_l[512];
  __shared__ float u1_l[256];
  __shared__ float red[4];
  const int b = blockIdx.x, t = threadIdx.x;
  const float Ss = Ssum[b];
#pragma unroll
  for (int h = 0; h < 2; h++) {
    int c = t + h * 256;
    u_l[c] = (t_arr[b * NC + c] * Ss + P[b * NC + c]) * (1.0f / 4096.0f);
  }
  __syncthreads();
  {
    float acc = 0.f;
    const float4* wr = (const float4*)(sk_w1 + (size_t)t * 512);
    for (int i = 0; i < 128; i++) {
      float4 w = wr[i];
      acc += w.x * u_l[i * 4] + w.y * u_l[i * 4 + 1] + w.z * u_l[i * 4 + 2] + w.w * u_l[i * 4 + 3];
    }
    u1_l[t] = fmaxf(acc, 0.0f);
  }
  __syncthreads();
  float u2[2];
#pragma unroll
  for (int h = 0; h < 2; h++) {
    int o = t + h * 256;
    float acc = 0.f;
    const float4* wr = (const float4*)(sk_w2 + (size_t)o * 256);
    for (int i = 0; i < 64; i++) {
      float4 w = wr[i];
      acc += w.x * u1_l[i * 4] + w.y * u1_l[i * 4 + 1] + w.z * u1_l[i * 4 + 2] + w.w * u1_l[i * 4 + 3];
    }
    u2[h] = fmaxf(acc, 0.0f);
  }
  float M = block_reduce_max(fmaxf(u2[0], u2[1]), red);
  float e0 = __expf(u2[0] - M), e1 = __expf(u2[1] - M);
  float Z = block_reduce_sum(e0 + e1, red);
  float inv = 1.0f / Z;
#pragma unroll
  for (int h = 0; h < 2; h++) {
    int o = t + h * 256;
    float a = (h == 0 ? e0 : e1) * inv;
    float tc = t_arr[b * NC + o];
    float Pv = P[b * NC + o];
    float c1 = a * tc;
    float c2 = 1.0f - a;
    float c3 = c1 * Ss + c2 * Pv;
    float4 cf = {c1, c2, c3, tc};
    *(float4*)(coef + (size_t)(b * NC + o) * 4) = cf;
  }
}

// K3: per b: Y = res_w(512x512) @ X(512x4096) via bf16 MFMA, fused epilogue
// out = x*sel + selected_sum + Y. Tile: full M=512 x N=64, 8 waves, K-loop BK=32.
__global__ __launch_bounds__(512, 1) void k3_gemm_epilogue(
    const unsigned short* __restrict__ wbf, const unsigned short* __restrict__ xT,
    const float* __restrict__ x, const float* __restrict__ s,
    const float* __restrict__ coef, float* __restrict__ out) {
  __shared__ short A_l[512 * 32];  // res_w tile [o][k]
  __shared__ short B_l[64 * 32];   // xT tile   [n][k]
  const int t = threadIdx.x;
  const int b = blockIdx.y;
  const int n0 = blockIdx.x * 64;
  const int w = t >> 6, l = t & 63;
  const int l16 = l & 15, quad = l >> 4;

  f32x4 acc[4][4];
#pragma unroll
  for (int mi = 0; mi < 4; mi++)
#pragma unroll
    for (int ni = 0; ni < 4; ni++) {
      f32x4 z = {0.f, 0.f, 0.f, 0.f};
      acc[mi][ni] = z;
    }

  const unsigned short* xTb = xT + (size_t)(b * HW + n0) * NC;

  for (int kk = 0; kk < 16; kk++) {
    const int k0 = kk * 32;
    short8 ra[4];
#pragma unroll
    for (int i = 0; i < 4; i++) {
      int seg = i * 512 + t;
      ra[i] = *(const short8*)(wbf + (size_t)(seg >> 2) * NC + k0 + (seg & 3) * 8);
    }
    short8 rb = {};
    if (t < 256) rb = *(const short8*)(xTb + (size_t)(t >> 2) * NC + k0 + (t & 3) * 8);
    __syncthreads();  // prev iter's LDS reads done
#pragma unroll
    for (int i = 0; i < 4; i++) *(short8*)&A_l[(i * 512 + t) * 8] = ra[i];
    if (t < 256) *(short8*)&B_l[t * 8] = rb;
    __syncthreads();  // tile staged
    short8 af[4], bfr[4];
#pragma unroll
    for (int mi = 0; mi < 4; mi++)
      af[mi] = *(const short8*)&A_l[(w * 64 + mi * 16 + l16) * 32 + quad * 8];
#pragma unroll
    for (int ni = 0; ni < 4; ni++)
      bfr[ni] = *(const short8*)&B_l[(ni * 16 + l16) * 32 + quad * 8];
#pragma unroll
    for (int mi = 0; mi < 4; mi++)
#pragma unroll
      for (int ni = 0; ni < 4; ni++)
        acc[mi][ni] = __builtin_amdgcn_mfma_f32_16x16x32_bf16(af[mi], bfr[ni], acc[mi][ni], 0, 0, 0);
  }

  // epilogue: D row = quad*4 + reg (o), col = l16 (n)
#pragma unroll
  for (int mi = 0; mi < 4; mi++) {
    float4 cf[4];
#pragma unroll
    for (int r = 0; r < 4; r++) {
      int o = w * 64 + mi * 16 + quad * 4 + r;
      cf[r] = *(const float4*)(coef + (size_t)(b * NC + o) * 4);
    }
#pragma unroll
    for (int ni = 0; ni < 4; ni++) {
      int n = n0 + ni * 16 + l16;
      float sv = s[b * HW + n];
#pragma unroll
      for (int r = 0; r < 4; r++) {
        int o = w * 64 + mi * 16 + quad * 4 + r;
        size_t idx = (size_t)(b * NC + o) * HW + n;
        float sel = cf[r].x * sv + cf[r].y * floorf((sv + cf[r].w) * 0.5f);
        out[idx] = x[idx] * sel + cf[r].z + acc[mi][ni][r];
      }
    }
  }
}

extern "C" void kernel_launch(void* const* d_in, const int* in_sizes, int n_in,
                              void* d_out, int out_size, void* d_ws, size_t ws_size,
                              hipStream_t stream) {
  const float* x       = (const float*)d_in[0];
  const float* w_b1    = (const float*)d_in[1];
  const float* b_b1    = (const float*)d_in[2];
  const float* w_b2    = (const float*)d_in[3];
  const float* b_b2    = (const float*)d_in[4];
  const float* w_conv1 = (const float*)d_in[5];
  const float* ln_g    = (const float*)d_in[6];
  const float* ln_b    = (const float*)d_in[7];
  const float* sk_w1   = (const float*)d_in[8];
  const float* sk_w2   = (const float*)d_in[9];
  const float* res_w   = (const float*)d_in[10];
  float* out = (float*)d_out;
  char* ws = (char*)d_ws;

  float* g_sum = (float*)(ws + 0x00000);          // 16 KB
  float* spat  = (float*)(ws + 0x08000);          // 128 KB
  float* Ssum  = (float*)(ws + 0x28000);          // 32 B
  float* s     = (float*)(ws + 0x30000);          // 128 KB
  float* t_arr = (float*)(ws + 0x50000);          // 16 KB
  float* P     = (float*)(ws + 0x54000);          // 16 KB
  float* coef  = (float*)(ws + 0x58000);          // 64 KB
  unsigned short* wbf = (unsigned short*)(ws + 0x68000);   // 512 KB
  unsigned short* xT  = (unsigned short*)(ws + 0x100000);  // 32 MB

  hipMemsetAsync(ws, 0, 0x28040, stream);  // zero g_sum, spat, Ssum
  k1_stats_transpose<<<dim3(64, 8, 8), 256, 0, stream>>>(x, w_conv1, g_sum, spat, xT);
  k2_prep<<<160, 256, 0, stream>>>(spat, s, Ssum, res_w, wbf);
  k2a_chain<<<8, 256, 0, stream>>>(g_sum, w_b1, b_b1, w_b2, b_b2, ln_g, ln_b, t_arr);
  k2b_floorsum<<<dim3(32, 8), 256, 0, stream>>>(s, t_arr, P);
  k2c_select<<<8, 256, 0, stream>>>(t_arr, P, Ssum, sk_w1, sk_w2, coef);
  k3_gemm_epilogue<<<dim3(64, 8), 512, 0, stream>>>(wbf, xT, x, s, coef, out);
}

// Round 3
// 253.585 us; speedup vs baseline: 1.0309x; 1.0309x over previous
//
#include <hip/hip_runtime.h>
#include <stdint.h>

#define HW 4096
#define NC 512
#define NB 8

typedef __attribute__((ext_vector_type(8))) short short8;
typedef __attribute__((ext_vector_type(4))) float f32x4;

__device__ __forceinline__ unsigned short f2bf(float f) {
  unsigned int u = __builtin_bit_cast(unsigned int, f);
  unsigned int r = (u + 0x7FFFu + ((u >> 16) & 1u)) >> 16;
  return (unsigned short)r;
}
__device__ __forceinline__ float hsig(float v) {
  return fminf(fmaxf((v + 3.0f) * (1.0f / 6.0f), 0.0f), 1.0f);
}

__device__ __forceinline__ float block_reduce_sum(float v, volatile float* red) {
  int t = threadIdx.x;
#pragma unroll
  for (int m = 1; m < 64; m <<= 1) v += __shfl_xor(v, m);
  if ((t & 63) == 0) red[t >> 6] = v;
  __syncthreads();
  v = red[0] + red[1] + red[2] + red[3];
  __syncthreads();
  return v;
}
__device__ __forceinline__ float block_reduce_max(float v, volatile float* red) {
  int t = threadIdx.x;
#pragma unroll
  for (int m = 1; m < 64; m <<= 1) v = fmaxf(v, __shfl_xor(v, m));
  if ((t & 63) == 0) red[t >> 6] = v;
  __syncthreads();
  v = fmaxf(fmaxf(red[0], red[1]), fmaxf(red[2], red[3]));
  __syncthreads();
  return v;
}

// K1: one pass over x. Per 64c x 64hw tile: partial g (atomic), partial spatial
// dot (atomic), and bf16 transpose-out in MFMA-fragment-swizzled layout:
// xTS tile (n16, k32) = 1KB, element (n=n16*16+(l&15), k=k32*32+(l>>4)*8+j) at
// tile*512 + l*8 shorts. Blocks with b==0 also convert res_w -> wbfS (same swizzle).
__global__ __launch_bounds__(256) void k1_stats_transpose(
    const float* __restrict__ x, const float* __restrict__ w_conv1,
    const float* __restrict__ res_w,
    float* __restrict__ g_sum, float* __restrict__ spat,
    unsigned short* __restrict__ xTS, unsigned short* __restrict__ wbfS) {
  __shared__ float sp_lds[16][64];
  __shared__ unsigned short t_lds[64 * 72];  // [hw][c], pad 72 (rows 144B)
  const int t = threadIdx.x;
  const int b = blockIdx.z;
  const int c0 = blockIdx.y * 64;
  const int h0 = blockIdx.x * 64;
  const int cg = t >> 4;   // 0..15 -> 4 c rows each
  const int hg = t & 15;   // 0..15 -> 4 hw each

  float vv[4][4];
  float wc[4];
  const float* xb = x + ((size_t)(b * NC + c0 + cg * 4) * HW) + h0 + hg * 4;
#pragma unroll
  for (int i = 0; i < 4; i++) {
    float4 v = *(const float4*)(xb + (size_t)i * HW);
    vv[i][0] = v.x; vv[i][1] = v.y; vv[i][2] = v.z; vv[i][3] = v.w;
    wc[i] = w_conv1[c0 + cg * 4 + i];
  }
  // g partial: reduce each c-row's 4hw sum across the 16 hg lanes (same wave)
#pragma unroll
  for (int i = 0; i < 4; i++) {
    float s = vv[i][0] + vv[i][1] + vv[i][2] + vv[i][3];
    s += __shfl_xor(s, 1); s += __shfl_xor(s, 2);
    s += __shfl_xor(s, 4); s += __shfl_xor(s, 8);
    if (hg == 0) atomicAdd(&g_sum[b * NC + c0 + cg * 4 + i], s);
  }
  // spatial partial
  {
    float4 sp;
    sp.x = vv[0][0] * wc[0] + vv[1][0] * wc[1] + vv[2][0] * wc[2] + vv[3][0] * wc[3];
    sp.y = vv[0][1] * wc[0] + vv[1][1] * wc[1] + vv[2][1] * wc[2] + vv[3][1] * wc[3];
    sp.z = vv[0][2] * wc[0] + vv[1][2] * wc[1] + vv[2][2] * wc[2] + vv[3][2] * wc[3];
    sp.w = vv[0][3] * wc[0] + vv[1][3] * wc[1] + vv[2][3] * wc[2] + vv[3][3] * wc[3];
    *(float4*)&sp_lds[cg][hg * 4] = sp;
  }
  // bf16 transpose into LDS: rows = hw, cols = c
#pragma unroll
  for (int j = 0; j < 4; j++) {
    ushort4 u;
    u.x = f2bf(vv[0][j]); u.y = f2bf(vv[1][j]);
    u.z = f2bf(vv[2][j]); u.w = f2bf(vv[3][j]);
    *(ushort4*)&t_lds[(hg * 4 + j) * 72 + cg * 4] = u;
  }
  __syncthreads();
  if (t < 64) {
    float s = 0.f;
#pragma unroll
    for (int i = 0; i < 16; i++) s += sp_lds[i][t];
    atomicAdd(&spat[b * HW + h0 + t], s);
  }
  // swizzled xTS write: 8 fragment tiles (4 n16 x 2 k32); wave w does tiles w, w+4.
  // Each wave-store = 1KB contiguous.
  const int w = t >> 6, l = t & 63;
#pragma unroll
  for (int ff = w; ff < 8; ff += 4) {
    const int fr = ff >> 1, fk = ff & 1;
    short8 v = *(const short8*)&t_lds[(fr * 16 + (l & 15)) * 72 + (fk * 4 + (l >> 4)) * 8];
    size_t tile = (size_t)(b * 256 + (h0 >> 4) + fr) * 16 + (c0 >> 5) + fk;
    *(short8*)(xTS + tile * 512 + l * 8) = v;
  }
  // res_w -> wbfS fragment swizzle, folded into the 512 b==0 blocks (row q each)
  if (b == 0 && t < 64) {
    const int q = blockIdx.y * 64 + blockIdx.x;  // o row 0..511
    float4 a = *(const float4*)(res_w + (size_t)q * 512 + t * 8);
    float4 c2 = *(const float4*)(res_w + (size_t)q * 512 + t * 8 + 4);
    short8 v;
    v[0] = (short)f2bf(a.x); v[1] = (short)f2bf(a.y);
    v[2] = (short)f2bf(a.z); v[3] = (short)f2bf(a.w);
    v[4] = (short)f2bf(c2.x); v[5] = (short)f2bf(c2.y);
    v[6] = (short)f2bf(c2.z); v[7] = (short)f2bf(c2.w);
    const int lq = (q & 15) + ((t & 3) << 4);
    *(short8*)(wbfS + ((size_t)(q >> 4) * 16 + (t >> 2)) * 512 + lq * 8) = v;
  }
}

// K2a (one block per batch): s = hsigmoid(spat), Ssum; g -> MLP -> hsig -> LN -> t
__global__ __launch_bounds__(256) void k2a_chain(
    const float* __restrict__ g_sum, const float* __restrict__ spat,
    const float* __restrict__ w_b1, const float* __restrict__ b_b1,
    const float* __restrict__ w_b2, const float* __restrict__ b_b2,
    const float* __restrict__ ln_g, const float* __restrict__ ln_b,
    float* __restrict__ s_out, float* __restrict__ Ssum, float* __restrict__ t_out) {
  __shared__ float g_l[512];
  __shared__ float ca1_l[256];
  __shared__ float red[4];
  const int b = blockIdx.x, t = threadIdx.x;
  float sl = 0.f;
#pragma unroll
  for (int i = 0; i < 4; i++) {
    int hw = t * 4 + i * 1024;
    float4 v = *(const float4*)(spat + b * HW + hw);
    float4 o;
    o.x = hsig(v.x); o.y = hsig(v.y); o.z = hsig(v.z); o.w = hsig(v.w);
    *(float4*)(s_out + b * HW + hw) = o;
    sl += o.x + o.y + o.z + o.w;
  }
  float Ss = block_reduce_sum(sl, red);
  if (t == 0) Ssum[b] = Ss;
#pragma unroll
  for (int h = 0; h < 2; h++) {
    int c = t + h * 256;
    g_l[c] = g_sum[b * NC + c] * (1.0f / 4096.0f);
  }
  __syncthreads();
  {
    float acc = b_b1[t];
    const float4* wr = (const float4*)(w_b1 + (size_t)t * 512);
    for (int i = 0; i < 128; i++) {
      float4 w = wr[i];
      acc += w.x * g_l[i * 4] + w.y * g_l[i * 4 + 1] + w.z * g_l[i * 4 + 2] + w.w * g_l[i * 4 + 3];
    }
    ca1_l[t] = fmaxf(acc, 0.0f);
  }
  __syncthreads();
  float ca[2];
#pragma unroll
  for (int h = 0; h < 2; h++) {
    int o = t + h * 256;
    float acc = b_b2[o];
    const float4* wr = (const float4*)(w_b2 + (size_t)o * 256);
    for (int i = 0; i < 64; i++) {
      float4 w = wr[i];
      acc += w.x * ca1_l[i * 4] + w.y * ca1_l[i * 4 + 1] + w.z * ca1_l[i * 4 + 2] + w.w * ca1_l[i * 4 + 3];
    }
    ca[h] = hsig(acc);
  }
  float S = block_reduce_sum(ca[0] + ca[1], red);
  float SQ = block_reduce_sum(ca[0] * ca[0] + ca[1] * ca[1], red);
  float mu = S * (1.0f / 512.0f);
  float var = SQ * (1.0f / 512.0f) - mu * mu;
  float rstd = rsqrtf(var + 1e-6f);
#pragma unroll
  for (int h = 0; h < 2; h++) {
    int o = t + h * 256;
    t_out[b * NC + o] = (ca[h] - mu) * rstd * ln_g[o] + ln_b[o];
  }
}

// K2b: P[b][c] = sum_hw floor((s + t)/2). s[b][:] staged once in LDS.
__global__ __launch_bounds__(256) void k2b_floorsum(
    const float* __restrict__ s, const float* __restrict__ t_arr, float* __restrict__ P) {
  __shared__ float s_l[4096];
  const int t = threadIdx.x;
  const int b = blockIdx.y;
  const int c0 = blockIdx.x * 16;
  const float* sb = s + b * HW;
#pragma unroll
  for (int i = 0; i < 16; i++) s_l[t + i * 256] = sb[t + i * 256];
  __syncthreads();
  const int w = t >> 6, l = t & 63;
#pragma unroll
  for (int j = 0; j < 4; j++) {
    int c = c0 + w * 4 + j;
    float tc = t_arr[b * NC + c];
    float sum = 0.f;
#pragma unroll 8
    for (int i = 0; i < 64; i++) sum += floorf((s_l[l + i * 64] + tc) * 0.5f);
#pragma unroll
    for (int m = 1; m < 64; m <<= 1) sum += __shfl_xor(sum, m);
    if (l == 0) P[b * NC + c] = sum;
  }
}

// K2c: u -> SK MLP -> softmax -> coef[b][c] = {a*t, 1-a, selected_sum, t}
__global__ __launch_bounds__(256) void k2c_select(
    const float* __restrict__ t_arr, const float* __restrict__ P,
    const float* __restrict__ Ssum, const float* __restrict__ sk_w1,
    const float* __restrict__ sk_w2, float* __restrict__ coef) {
  __shared__ float u_l[512];
  __shared__ float u1_l[256];
  __shared__ float red[4];
  const int b = blockIdx.x, t = threadIdx.x;
  const float Ss = Ssum[b];
#pragma unroll
  for (int h = 0; h < 2; h++) {
    int c = t + h * 256;
    u_l[c] = (t_arr[b * NC + c] * Ss + P[b * NC + c]) * (1.0f / 4096.0f);
  }
  __syncthreads();
  {
    float acc = 0.f;
    const float4* wr = (const float4*)(sk_w1 + (size_t)t * 512);
    for (int i = 0; i < 128; i++) {
      float4 w = wr[i];
      acc += w.x * u_l[i * 4] + w.y * u_l[i * 4 + 1] + w.z * u_l[i * 4 + 2] + w.w * u_l[i * 4 + 3];
    }
    u1_l[t] = fmaxf(acc, 0.0f);
  }
  __syncthreads();
  float u2[2];
#pragma unroll
  for (int h = 0; h < 2; h++) {
    int o = t + h * 256;
    float acc = 0.f;
    const float4* wr = (const float4*)(sk_w2 + (size_t)o * 256);
    for (int i = 0; i < 64; i++) {
      float4 w = wr[i];
      acc += w.x * u1_l[i * 4] + w.y * u1_l[i * 4 + 1] + w.z * u1_l[i * 4 + 2] + w.w * u1_l[i * 4 + 3];
    }
    u2[h] = fmaxf(acc, 0.0f);
  }
  float M = block_reduce_max(fmaxf(u2[0], u2[1]), red);
  float e0 = __expf(u2[0] - M), e1 = __expf(u2[1] - M);
  float Z = block_reduce_sum(e0 + e1, red);
  float inv = 1.0f / Z;
#pragma unroll
  for (int h = 0; h < 2; h++) {
    int o = t + h * 256;
    float a = (h == 0 ? e0 : e1) * inv;
    float tc = t_arr[b * NC + o];
    float Pv = P[b * NC + o];
    float c1 = a * tc;
    float c2 = 1.0f - a;
    float c3 = c1 * Ss + c2 * Pv;
    float4 cf = {c1, c2, c3, tc};
    *(float4*)(coef + (size_t)(b * NC + o) * 4) = cf;
  }
}

// K3: per b: Y = res_w(512x512) @ X(512x4096), bf16 MFMA, LDS-free barrier-free
// K-loop: operands pre-swizzled so each fragment load is one coalesced 1KB
// global_load_dwordx4 per wave. Epilogue fused: out = x*sel + c3 + Y.
__global__ __launch_bounds__(512, 4) void k3_gemm_epilogue(
    const unsigned short* __restrict__ wbfS, const unsigned short* __restrict__ xTS,
    const float* __restrict__ x, const float* __restrict__ s,
    const float* __restrict__ coef, float* __restrict__ out) {
  const int t = threadIdx.x;
  const int b = blockIdx.y;
  const int bx = blockIdx.x;
  const int w = t >> 6, l = t & 63;
  const int l16 = l & 15, quad = l >> 4;

  f32x4 acc[4][4];
#pragma unroll
  for (int mi = 0; mi < 4; mi++)
#pragma unroll
    for (int ni = 0; ni < 4; ni++) {
      f32x4 z = {0.f, 0.f, 0.f, 0.f};
      acc[mi][ni] = z;
    }

  const unsigned short* Ab = wbfS + (size_t)(w * 4) * 16 * 512 + l * 8;
  const unsigned short* Bb = xTS + (size_t)(b * 256 + bx * 4) * 16 * 512 + l * 8;

#pragma unroll 2
  for (int kk = 0; kk < 16; kk++) {
    short8 af[4], bfr[4];
#pragma unroll
    for (int mi = 0; mi < 4; mi++)
      af[mi] = *(const short8*)(Ab + ((size_t)mi * 16 + kk) * 512);
#pragma unroll
    for (int ni = 0; ni < 4; ni++)
      bfr[ni] = *(const short8*)(Bb + ((size_t)ni * 16 + kk) * 512);
#pragma unroll
    for (int mi = 0; mi < 4; mi++)
#pragma unroll
      for (int ni = 0; ni < 4; ni++)
        acc[mi][ni] = __builtin_amdgcn_mfma_f32_16x16x32_bf16(af[mi], bfr[ni], acc[mi][ni], 0, 0, 0);
  }

  // epilogue: D row = quad*4 + r (o), col = l16 (n); row-outer order so the
  // 4 ni stores per row are consecutive 64B chunks of one 256B span.
  const int n0 = bx * 64;
  float sv[4];
#pragma unroll
  for (int ni = 0; ni < 4; ni++) sv[ni] = s[b * HW + n0 + ni * 16 + l16];
#pragma unroll
  for (int mi = 0; mi < 4; mi++) {
#pragma unroll
    for (int r = 0; r < 4; r++) {
      const int o = w * 64 + mi * 16 + quad * 4 + r;
      float4 cf = *(const float4*)(coef + (size_t)(b * NC + o) * 4);
      const size_t row = (size_t)(b * NC + o) * HW + n0;
#pragma unroll
      for (int ni = 0; ni < 4; ni++) {
        const int nn = ni * 16 + l16;
        float sel = cf.x * sv[ni] + cf.y * floorf((sv[ni] + cf.w) * 0.5f);
        out[row + nn] = x[row + nn] * sel + cf.z + acc[mi][ni][r];
      }
    }
  }
}

extern "C" void kernel_launch(void* const* d_in, const int* in_sizes, int n_in,
                              void* d_out, int out_size, void* d_ws, size_t ws_size,
                              hipStream_t stream) {
  const float* x       = (const float*)d_in[0];
  const float* w_b1    = (const float*)d_in[1];
  const float* b_b1    = (const float*)d_in[2];
  const float* w_b2    = (const float*)d_in[3];
  const float* b_b2    = (const float*)d_in[4];
  const float* w_conv1 = (const float*)d_in[5];
  const float* ln_g    = (const float*)d_in[6];
  const float* ln_b    = (const float*)d_in[7];
  const float* sk_w1   = (const float*)d_in[8];
  const float* sk_w2   = (const float*)d_in[9];
  const float* res_w   = (const float*)d_in[10];
  float* out = (float*)d_out;
  char* ws = (char*)d_ws;

  float* g_sum = (float*)(ws + 0x00000);          // 16 KB  (atomic)
  float* spat  = (float*)(ws + 0x08000);          // 128 KB (atomic)
  float* Ssum  = (float*)(ws + 0x28000);          // 32 B
  float* t_arr = (float*)(ws + 0x29000);          // 16 KB
  float* P     = (float*)(ws + 0x30000);          // 16 KB
  float* coef  = (float*)(ws + 0x38000);          // 64 KB
  float* s     = (float*)(ws + 0x50000);          // 128 KB
  unsigned short* wbfS = (unsigned short*)(ws + 0x80000);   // 512 KB
  unsigned short* xTS  = (unsigned short*)(ws + 0x100000);  // 32 MB

  hipMemsetAsync(ws, 0, 0x28000, stream);  // zero g_sum, spat
  k1_stats_transpose<<<dim3(64, 8, 8), 256, 0, stream>>>(x, w_conv1, res_w, g_sum, spat, xTS, wbfS);
  k2a_chain<<<8, 256, 0, stream>>>(g_sum, spat, w_b1, b_b1, w_b2, b_b2, ln_g, ln_b, s, Ssum, t_arr);
  k2b_floorsum<<<dim3(32, 8), 256, 0, stream>>>(s, t_arr, P);
  k2c_select<<<8, 256, 0, stream>>>(t_arr, P, Ssum, sk_w1, sk_w2, coef);
  k3_gemm_epilogue<<<dim3(64, 8), 512, 0, stream>>>(wbfS, xTS, x, s, coef, out);
}

// Round 4
// 249.442 us; speedup vs baseline: 1.0480x; 1.0166x over previous
//
#include <hip/hip_runtime.h>
#include <stdint.h>

#define HW 4096
#define NC 512
#define NB 8

typedef __attribute__((ext_vector_type(8))) short short8;
typedef __attribute__((ext_vector_type(4))) float f32x4;

__device__ __forceinline__ unsigned short f2bf(float f) {
  unsigned int u = __builtin_bit_cast(unsigned int, f);
  unsigned int r = (u + 0x7FFFu + ((u >> 16) & 1u)) >> 16;
  return (unsigned short)r;
}
__device__ __forceinline__ float hsig(float v) {
  return fminf(fmaxf((v + 3.0f) * (1.0f / 6.0f), 0.0f), 1.0f);
}

__device__ __forceinline__ float block_reduce_sum(float v, volatile float* red) {
  int t = threadIdx.x;
#pragma unroll
  for (int m = 1; m < 64; m <<= 1) v += __shfl_xor(v, m);
  if ((t & 63) == 0) red[t >> 6] = v;
  __syncthreads();
  v = red[0] + red[1] + red[2] + red[3];
  __syncthreads();
  return v;
}
__device__ __forceinline__ float block_reduce_max(float v, volatile float* red) {
  int t = threadIdx.x;
#pragma unroll
  for (int m = 1; m < 64; m <<= 1) v = fmaxf(v, __shfl_xor(v, m));
  if ((t & 63) == 0) red[t >> 6] = v;
  __syncthreads();
  v = fmaxf(fmaxf(red[0], red[1]), fmaxf(red[2], red[3]));
  __syncthreads();
  return v;
}

// Pipelined dot: 4 independent chains, deep unroll -> many loads in flight.
__device__ __forceinline__ float dot_chunks(const float4* __restrict__ wr,
                                            const float4* __restrict__ vl,
                                            int nchunks) {
  float p0 = 0.f, p1 = 0.f, p2 = 0.f, p3 = 0.f;
#pragma unroll 8
  for (int i = 0; i < nchunks; i += 4) {
    float4 w0 = wr[i], w1 = wr[i + 1], w2 = wr[i + 2], w3 = wr[i + 3];
    float4 a0 = vl[i], a1 = vl[i + 1], a2 = vl[i + 2], a3 = vl[i + 3];
    p0 += w0.x * a0.x + w0.y * a0.y + w0.z * a0.z + w0.w * a0.w;
    p1 += w1.x * a1.x + w1.y * a1.y + w1.z * a1.z + w1.w * a1.w;
    p2 += w2.x * a2.x + w2.y * a2.y + w2.z * a2.z + w2.w * a2.w;
    p3 += w3.x * a3.x + w3.y * a3.y + w3.z * a3.z + w3.w * a3.w;
  }
  return (p0 + p1) + (p2 + p3);
}

// K1: one pass over x. Per 64c x 64hw tile: partial g (atomic), partial spatial
// dot (atomic), and bf16 transpose-out in MFMA-fragment-swizzled layout.
// Blocks with b==0 also convert res_w -> wbfS (same swizzle).
__global__ __launch_bounds__(256) void k1_stats_transpose(
    const float* __restrict__ x, const float* __restrict__ w_conv1,
    const float* __restrict__ res_w,
    float* __restrict__ g_sum, float* __restrict__ spat,
    unsigned short* __restrict__ xTS, unsigned short* __restrict__ wbfS) {
  __shared__ float sp_lds[16][64];
  __shared__ unsigned short t_lds[64 * 72];  // [hw][c], pad 72
  const int t = threadIdx.x;
  const int b = blockIdx.z;
  const int c0 = blockIdx.y * 64;
  const int h0 = blockIdx.x * 64;
  const int cg = t >> 4;
  const int hg = t & 15;

  float vv[4][4];
  float wc[4];
  const float* xb = x + ((size_t)(b * NC + c0 + cg * 4) * HW) + h0 + hg * 4;
#pragma unroll
  for (int i = 0; i < 4; i++) {
    float4 v = *(const float4*)(xb + (size_t)i * HW);
    vv[i][0] = v.x; vv[i][1] = v.y; vv[i][2] = v.z; vv[i][3] = v.w;
    wc[i] = w_conv1[c0 + cg * 4 + i];
  }
#pragma unroll
  for (int i = 0; i < 4; i++) {
    float s = vv[i][0] + vv[i][1] + vv[i][2] + vv[i][3];
    s += __shfl_xor(s, 1); s += __shfl_xor(s, 2);
    s += __shfl_xor(s, 4); s += __shfl_xor(s, 8);
    if (hg == 0) atomicAdd(&g_sum[b * NC + c0 + cg * 4 + i], s);
  }
  {
    float4 sp;
    sp.x = vv[0][0] * wc[0] + vv[1][0] * wc[1] + vv[2][0] * wc[2] + vv[3][0] * wc[3];
    sp.y = vv[0][1] * wc[0] + vv[1][1] * wc[1] + vv[2][1] * wc[2] + vv[3][1] * wc[3];
    sp.z = vv[0][2] * wc[0] + vv[1][2] * wc[1] + vv[2][2] * wc[2] + vv[3][2] * wc[3];
    sp.w = vv[0][3] * wc[0] + vv[1][3] * wc[1] + vv[2][3] * wc[2] + vv[3][3] * wc[3];
    *(float4*)&sp_lds[cg][hg * 4] = sp;
  }
#pragma unroll
  for (int j = 0; j < 4; j++) {
    ushort4 u;
    u.x = f2bf(vv[0][j]); u.y = f2bf(vv[1][j]);
    u.z = f2bf(vv[2][j]); u.w = f2bf(vv[3][j]);
    *(ushort4*)&t_lds[(hg * 4 + j) * 72 + cg * 4] = u;
  }
  __syncthreads();
  if (t < 64) {
    float s = 0.f;
#pragma unroll
    for (int i = 0; i < 16; i++) s += sp_lds[i][t];
    atomicAdd(&spat[b * HW + h0 + t], s);
  }
  const int w = t >> 6, l = t & 63;
#pragma unroll
  for (int ff = w; ff < 8; ff += 4) {
    const int fr = ff >> 1, fk = ff & 1;
    short8 v = *(const short8*)&t_lds[(fr * 16 + (l & 15)) * 72 + (fk * 4 + (l >> 4)) * 8];
    size_t tile = (size_t)(b * 256 + (h0 >> 4) + fr) * 16 + (c0 >> 5) + fk;
    *(short8*)(xTS + tile * 512 + l * 8) = v;
  }
  if (b == 0 && t < 64) {
    const int q = blockIdx.y * 64 + blockIdx.x;  // o row 0..511
    float4 a = *(const float4*)(res_w + (size_t)q * 512 + t * 8);
    float4 c2 = *(const float4*)(res_w + (size_t)q * 512 + t * 8 + 4);
    short8 v;
    v[0] = (short)f2bf(a.x); v[1] = (short)f2bf(a.y);
    v[2] = (short)f2bf(a.z); v[3] = (short)f2bf(a.w);
    v[4] = (short)f2bf(c2.x); v[5] = (short)f2bf(c2.y);
    v[6] = (short)f2bf(c2.z); v[7] = (short)f2bf(c2.w);
    const int lq = (q & 15) + ((t & 3) << 4);
    *(short8*)(wbfS + ((size_t)(q >> 4) * 16 + (t >> 2)) * 512 + lq * 8) = v;
  }
}

// K2a (32 blocks = 4 per batch): s = hsigmoid(spat) + Ssum (atomic), and
// mv1: ca1 = relu(w_b1 @ g + b_b1). 4 threads per output, pipelined dot.
__global__ __launch_bounds__(256) void k2a_mv1(
    const float* __restrict__ g_sum, const float* __restrict__ spat,
    const float* __restrict__ w_b1, const float* __restrict__ b_b1,
    float* __restrict__ s_out, float* __restrict__ Ssum, float* __restrict__ ca1) {
  __shared__ float g_l[512];
  const int t = threadIdx.x;
  const int b = blockIdx.x >> 2, q = blockIdx.x & 3;
  // s + Ssum for this quarter
  {
    int idx = b * HW + q * 1024 + t * 4;
    float4 v = *(const float4*)(spat + idx);
    float4 o;
    o.x = hsig(v.x); o.y = hsig(v.y); o.z = hsig(v.z); o.w = hsig(v.w);
    *(float4*)(s_out + idx) = o;
    float sum = o.x + o.y + o.z + o.w;
#pragma unroll
    for (int m = 1; m < 64; m <<= 1) sum += __shfl_xor(sum, m);
    if ((t & 63) == 0) atomicAdd(&Ssum[b], sum);
  }
  // g into LDS
  g_l[t] = g_sum[b * NC + t] * (1.0f / 4096.0f);
  g_l[t + 256] = g_sum[b * NC + t + 256] * (1.0f / 4096.0f);
  __syncthreads();
  const int o = q * 64 + (t >> 2), kq = t & 3;
  float sum = dot_chunks((const float4*)(w_b1 + (size_t)o * 512 + kq * 128),
                         (const float4*)(g_l + kq * 128), 32);
  sum += __shfl_xor(sum, 1);
  sum += __shfl_xor(sum, 2);
  if (kq == 0) ca1[b * 256 + o] = fmaxf(sum + b_b1[o], 0.0f);
}

// K2mv2 (8 blocks): ca2 = hsigmoid(w_b2 @ ca1 + b_b2); LayerNorm -> t_arr
__global__ __launch_bounds__(256) void k2_mv2_ln(
    const float* __restrict__ ca1, const float* __restrict__ w_b2,
    const float* __restrict__ b_b2, const float* __restrict__ ln_g,
    const float* __restrict__ ln_b, float* __restrict__ t_out) {
  __shared__ float ca1_l[256];
  __shared__ float red[4];
  const int b = blockIdx.x, t = threadIdx.x;
  ca1_l[t] = ca1[b * 256 + t];
  __syncthreads();
  float ca[2];
#pragma unroll
  for (int h = 0; h < 2; h++) {
    int o = t + h * 256;
    float acc = dot_chunks((const float4*)(w_b2 + (size_t)o * 256),
                           (const float4*)ca1_l, 64);
    ca[h] = hsig(acc + b_b2[o]);
  }
  float S = block_reduce_sum(ca[0] + ca[1], red);
  float SQ = block_reduce_sum(ca[0] * ca[0] + ca[1] * ca[1], red);
  float mu = S * (1.0f / 512.0f);
  float var = SQ * (1.0f / 512.0f) - mu * mu;
  float rstd = rsqrtf(var + 1e-6f);
#pragma unroll
  for (int h = 0; h < 2; h++) {
    int o = t + h * 256;
    t_out[b * NC + o] = (ca[h] - mu) * rstd * ln_g[o] + ln_b[o];
  }
}

// K2bF: P[b][c] = sum_hw floor((s + t)/2). s[b][:] staged once in LDS.
__global__ __launch_bounds__(256) void k2b_floorsum(
    const float* __restrict__ s, const float* __restrict__ t_arr, float* __restrict__ P) {
  __shared__ float s_l[4096];
  const int t = threadIdx.x;
  const int b = blockIdx.y;
  const int c0 = blockIdx.x * 16;
  const float* sb = s + b * HW;
#pragma unroll
  for (int i = 0; i < 16; i++) s_l[t + i * 256] = sb[t + i * 256];
  __syncthreads();
  const int w = t >> 6, l = t & 63;
#pragma unroll
  for (int j = 0; j < 4; j++) {
    int c = c0 + w * 4 + j;
    float tc = t_arr[b * NC + c];
    float sum = 0.f;
#pragma unroll 8
    for (int i = 0; i < 64; i++) sum += floorf((s_l[l + i * 64] + tc) * 0.5f);
#pragma unroll
    for (int m = 1; m < 64; m <<= 1) sum += __shfl_xor(sum, m);
    if (l == 0) P[b * NC + c] = sum;
  }
}

// K2c1 (32 blocks): u = (t*Ss + P)/4096; u1 = relu(sk_w1 @ u)
__global__ __launch_bounds__(256) void k2c1_mv(
    const float* __restrict__ t_arr, const float* __restrict__ P,
    const float* __restrict__ Ssum, const float* __restrict__ sk_w1,
    float* __restrict__ u1) {
  __shared__ float u_l[512];
  const int t = threadIdx.x;
  const int b = blockIdx.x >> 2, q = blockIdx.x & 3;
  const float Ss = Ssum[b];
#pragma unroll
  for (int h = 0; h < 2; h++) {
    int c = t + h * 256;
    u_l[c] = (t_arr[b * NC + c] * Ss + P[b * NC + c]) * (1.0f / 4096.0f);
  }
  __syncthreads();
  const int o = q * 64 + (t >> 2), kq = t & 3;
  float sum = dot_chunks((const float4*)(sk_w1 + (size_t)o * 512 + kq * 128),
                         (const float4*)(u_l + kq * 128), 32);
  sum += __shfl_xor(sum, 1);
  sum += __shfl_xor(sum, 2);
  if (kq == 0) u1[b * 256 + o] = fmaxf(sum, 0.0f);
}

// K2c2 (8 blocks): u2 = relu(sk_w2 @ u1); softmax; coef = {a*t, 1-a, sel_sum, t}
__global__ __launch_bounds__(256) void k2c2_select(
    const float* __restrict__ u1, const float* __restrict__ sk_w2,
    const float* __restrict__ t_arr, const float* __restrict__ P,
    const float* __restrict__ Ssum, float* __restrict__ coef) {
  __shared__ float u1_l[256];
  __shared__ float red[4];
  const int b = blockIdx.x, t = threadIdx.x;
  const float Ss = Ssum[b];
  u1_l[t] = u1[b * 256 + t];
  __syncthreads();
  float u2[2];
#pragma unroll
  for (int h = 0; h < 2; h++) {
    int o = t + h * 256;
    float acc = dot_chunks((const float4*)(sk_w2 + (size_t)o * 256),
                           (const float4*)u1_l, 64);
    u2[h] = fmaxf(acc, 0.0f);
  }
  float M = block_reduce_max(fmaxf(u2[0], u2[1]), red);
  float e0 = __expf(u2[0] - M), e1 = __expf(u2[1] - M);
  float Z = block_reduce_sum(e0 + e1, red);
  float inv = 1.0f / Z;
#pragma unroll
  for (int h = 0; h < 2; h++) {
    int o = t + h * 256;
    float a = (h == 0 ? e0 : e1) * inv;
    float tc = t_arr[b * NC + o];
    float Pv = P[b * NC + o];
    float c1 = a * tc;
    float c2 = 1.0f - a;
    float c3 = c1 * Ss + c2 * Pv;
    float4 cf = {c1, c2, c3, tc};
    *(float4*)(coef + (size_t)(b * NC + o) * 4) = cf;
  }
}

// K3: Y = res_w @ X per batch, bf16 MFMA, LDS-free barrier-free K-loop.
// M split in 2 (grid 64 x 2 x 8 = 1024 blocks); wave tile 32x64 -> acc 32 regs,
// leaving VGPR headroom for deep prefetch at 3 waves/EU. Epilogue transposes
// acc through per-wave LDS (wave-synchronous) for float4 x/out accesses.
__global__ __launch_bounds__(512, 3) void k3_gemm_epilogue(
    const unsigned short* __restrict__ wbfS, const unsigned short* __restrict__ xTS,
    const float* __restrict__ x, const float* __restrict__ s,
    const float* __restrict__ coef, float* __restrict__ out) {
  __shared__ float eplds[8 * 16 * 68];  // 16 rows x 68 stride per wave
  const int t = threadIdx.x;
  const int bx = blockIdx.x, mz = blockIdx.y, b = blockIdx.z;
  const int w = t >> 6, l = t & 63;
  const int l16 = l & 15, quad = l >> 4;

  f32x4 acc[2][4];
#pragma unroll
  for (int mi = 0; mi < 2; mi++)
#pragma unroll
    for (int ni = 0; ni < 4; ni++) {
      f32x4 z = {0.f, 0.f, 0.f, 0.f};
      acc[mi][ni] = z;
    }

  const unsigned short* Ab = wbfS + ((size_t)(mz * 16 + w * 2) * 16) * 512 + l * 8;
  const unsigned short* Bb = xTS + ((size_t)(b * 256 + bx * 4) * 16) * 512 + l * 8;

#pragma unroll 4
  for (int kk = 0; kk < 16; kk++) {
    short8 af[2], bfr[4];
#pragma unroll
    for (int mi = 0; mi < 2; mi++)
      af[mi] = *(const short8*)(Ab + ((size_t)mi * 16 + kk) * 512);
#pragma unroll
    for (int ni = 0; ni < 4; ni++)
      bfr[ni] = *(const short8*)(Bb + ((size_t)ni * 16 + kk) * 512);
#pragma unroll
    for (int mi = 0; mi < 2; mi++)
#pragma unroll
      for (int ni = 0; ni < 4; ni++)
        acc[mi][ni] = __builtin_amdgcn_mfma_f32_16x16x32_bf16(af[mi], bfr[ni], acc[mi][ni], 0, 0, 0);
  }

  const int n0 = bx * 64;
  float* eb = &eplds[w * 1088];
  const int row = l >> 2, cb = (l & 3) * 16;
#pragma unroll
  for (int mi = 0; mi < 2; mi++) {
    // scatter acc (D: row=quad*4+r, col=l16) into wave-private LDS tile
#pragma unroll
    for (int ni = 0; ni < 4; ni++)
#pragma unroll
      for (int r = 0; r < 4; r++)
        eb[(quad * 4 + r) * 68 + ni * 16 + l16] = acc[mi][ni][r];
    // gather: lane handles row=l>>2, cols cb..cb+15 (4x float4) — wave-sync via LDS order
    const int o = mz * 256 + w * 32 + mi * 16 + row;
    float4 cf = *(const float4*)(coef + (size_t)(b * NC + o) * 4);
    const size_t rbase = (size_t)(b * NC + o) * HW + n0 + cb;
    const float* sp = s + b * HW + n0 + cb;
#pragma unroll
    for (int j = 0; j < 4; j++) {
      f32x4 y = *(f32x4*)&eb[row * 68 + cb + 4 * j];
      float4 sv = *(const float4*)(sp + 4 * j);
      float4 xv = *(const float4*)(x + rbase + 4 * j);
      float4 ov;
      ov.x = xv.x * (cf.x * sv.x + cf.y * floorf((sv.x + cf.w) * 0.5f)) + cf.z + y.x;
      ov.y = xv.y * (cf.x * sv.y + cf.y * floorf((sv.y + cf.w) * 0.5f)) + cf.z + y.y;
      ov.z = xv.z * (cf.x * sv.z + cf.y * floorf((sv.z + cf.w) * 0.5f)) + cf.z + y.z;
      ov.w = xv.w * (cf.x * sv.w + cf.y * floorf((sv.w + cf.w) * 0.5f)) + cf.z + y.w;
      *(float4*)(out + rbase + 4 * j) = ov;
    }
  }
}

extern "C" void kernel_launch(void* const* d_in, const int* in_sizes, int n_in,
                              void* d_out, int out_size, void* d_ws, size_t ws_size,
                              hipStream_t stream) {
  const float* x       = (const float*)d_in[0];
  const float* w_b1    = (const float*)d_in[1];
  const float* b_b1    = (const float*)d_in[2];
  const float* w_b2    = (const float*)d_in[3];
  const float* b_b2    = (const float*)d_in[4];
  const float* w_conv1 = (const float*)d_in[5];
  const float* ln_g    = (const float*)d_in[6];
  const float* ln_b    = (const float*)d_in[7];
  const float* sk_w1   = (const float*)d_in[8];
  const float* sk_w2   = (const float*)d_in[9];
  const float* res_w   = (const float*)d_in[10];
  float* out = (float*)d_out;
  char* ws = (char*)d_ws;

  float* g_sum = (float*)(ws + 0x00000);          // 16 KB  (atomic)
  float* spat  = (float*)(ws + 0x08000);          // 128 KB (atomic)
  float* Ssum  = (float*)(ws + 0x28000);          // 32 B   (atomic)
  float* t_arr = (float*)(ws + 0x29000);          // 16 KB
  float* P     = (float*)(ws + 0x30000);          // 16 KB
  float* coef  = (float*)(ws + 0x38000);          // 64 KB
  float* s     = (float*)(ws + 0x50000);          // 128 KB
  float* ca1   = (float*)(ws + 0x70000);          // 8 KB
  float* u1    = (float*)(ws + 0x72000);          // 8 KB
  unsigned short* wbfS = (unsigned short*)(ws + 0x80000);   // 512 KB
  unsigned short* xTS  = (unsigned short*)(ws + 0x100000);  // 32 MB

  hipMemsetAsync(ws, 0, 0x28040, stream);  // zero g_sum, spat, Ssum
  k1_stats_transpose<<<dim3(64, 8, 8), 256, 0, stream>>>(x, w_conv1, res_w, g_sum, spat, xTS, wbfS);
  k2a_mv1<<<32, 256, 0, stream>>>(g_sum, spat, w_b1, b_b1, s, Ssum, ca1);
  k2_mv2_ln<<<8, 256, 0, stream>>>(ca1, w_b2, b_b2, ln_g, ln_b, t_arr);
  k2b_floorsum<<<dim3(32, 8), 256, 0, stream>>>(s, t_arr, P);
  k2c1_mv<<<32, 256, 0, stream>>>(t_arr, P, Ssum, sk_w1, u1);
  k2c2_select<<<8, 256, 0, stream>>>(u1, sk_w2, t_arr, P, Ssum, coef);
  k3_gemm_epilogue<<<dim3(64, 2, 8), 512, 0, stream>>>(wbfS, xTS, x, s, coef, out);
}